// Round 1
// 476.984 us; speedup vs baseline: 1.0906x; 1.0906x over previous
//
#include <hip/hip_runtime.h>
#include <stdint.h>

// TemporalAttention: windowed causal attention, B=16 T=4096 C=512 H=8 hd=64 W=128
// R4: GEMMs rebuilt as 256x128x64 3-deep pipelined (144KB LDS, 8 waves):
//     one raw s_barrier per K-step, counted s_waitcnt vmcnt(6) (never 0 in
//     steady state), setprio(1) around the 32-MFMA cluster (T3+T4+T5), and
//     XCD-chunked n-fastest grid (T1) so the 12 (qkv) / 4 (proj) blocks that
//     share an A-panel co-run on one XCD's L2 -> FETCH 399MB -> ~85MB expected.
//     Pipeline safety: stage(t+2) writes buf[(t+2)%3] == buf[(t-1)%3], whose
//     reads completed at step t-1's lgkmcnt(0) before its barrier; reads(t)
//     are validated by step t-1's vmcnt(6)+barrier (stage(t) is the oldest 6
//     outstanding vmem ops on every wave). attn kernel unchanged from R3.
// Workspace layout (bytes):
//   x_bf16    @ 0          : 67108864   (65536 x 512 bf16)
//   qk_ws     @ 67108864   : 134217728  (65536 x 1024 bf16: cols 0-511 Q, 512-1023 K)
//   vT_ws     @ 201326592  : 67108864   (512 win x 8 h x 64 d x 128 t bf16)
//   attn_ws   @ 268435456  : 67108864   (65536 x 512 bf16)
//   wqkv_bf   @ 335544320  : 1572864
//   wproj_bf  @ 337117184  : 524288

typedef unsigned short ushort_t;
typedef __attribute__((ext_vector_type(8))) short short8;
typedef __attribute__((ext_vector_type(4))) float f32x4;
typedef __attribute__((ext_vector_type(4))) float f4v;
typedef __attribute__((ext_vector_type(4))) unsigned short us4;

static __device__ __forceinline__ unsigned short f2bf(float f) {
  unsigned int u = __float_as_uint(f);
  u += 0x7FFFu + ((u >> 16) & 1u);   // RNE
  return (unsigned short)(u >> 16);
}

static __device__ __forceinline__ void gl_lds16(const ushort_t* g, ushort_t* l) {
  __builtin_amdgcn_global_load_lds(
      (const __attribute__((address_space(1))) void*)g,
      (__attribute__((address_space(3))) void*)l, 16, 0, 0);
}

// ---------------- cast fp32 -> bf16 (vectorized) ----------------
__global__ __launch_bounds__(256) void cast_f32_bf16(const float* __restrict__ in,
                                                     ushort_t* __restrict__ out, int n4) {
  int i = blockIdx.x * 256 + threadIdx.x;
  if (i >= n4) return;
  f4v v = ((const f4v*)in)[i];
  us4 o;
  o.x = f2bf(v.x); o.y = f2bf(v.y); o.z = f2bf(v.z); o.w = f2bf(v.w);
  ((us4*)out)[i] = o;
}

// ---------------- QKV GEMM: [65536,512] x [1536,512]^T -> qk_ws / vT_ws ----------------
// BM=256 BN=128 BK=64, 512 thr (8 waves, 4m x 2n, 64x64 out each).
// 3-deep LDS pipeline: buffers of (A 256x64 + B 128x64) bf16 = 48KB, x3 = 144KB.
// Per K-step: ds_read 16 frags, issue stage(t+2) [6 gl_lds16/thread],
// vmcnt(6) [= stage(t+1) still in flight], lgkmcnt(0), s_barrier, 32 MFMA.
// Grid: 3072 linear blocks, XCD-chunked (384/XCD), n-fastest within chunk.
__global__ __launch_bounds__(512, 2) void qkv_gemm(const ushort_t* __restrict__ A,
                                                   const ushort_t* __restrict__ B,
                                                   ushort_t* __restrict__ qk,
                                                   ushort_t* __restrict__ vT) {
  __shared__ __align__(16) ushort_t smem[3 * 24576];   // 144 KB
  const int tid = threadIdx.x;
  const int lane = tid & 63;
  const int wv = tid >> 6;
  const int wr = wv >> 1, wc = wv & 1;
  const int lr = lane & 15;
  const int lg = lane >> 4;

  // XCD-chunked n-fastest decode: 3072 blocks, 8 XCDs, 384/chunk, 12 n-tiles.
  const int bid = blockIdx.x;
  const int wg = (bid & 7) * 384 + (bid >> 3);
  const int nb = wg % 12;
  const int mb = wg / 12;
  const int m0 = mb << 8;
  const int n0 = nb << 7;

  // staging addresses: granule g = r*512 + tid; row = r*64 + (tid>>3), ch = tid&7;
  // LDS dest linear, global source chunk pre-swizzled (ch ^ (row&7)).
  const int srow = tid >> 3;                    // 0..63
  const int ssw  = (((tid & 7) ^ (srow & 7)) << 3);
  const ushort_t* gA = A + (size_t)(m0 + srow) * 512 + ssw;
  const ushort_t* gB = B + (size_t)(n0 + srow) * 512 + ssw;

  f32x4 acc[4][4] = {};

  auto STAGE = [&](int t, int q) {
    ushort_t* Ab = smem + q * 24576;
    ushort_t* Bb = Ab + 16384;
    const int kk = t << 6;
#pragma unroll
    for (int r = 0; r < 4; ++r)
      gl_lds16(gA + (size_t)(r * 64) * 512 + kk, Ab + (r * 512 + wv * 64) * 8);
#pragma unroll
    for (int r = 0; r < 2; ++r)
      gl_lds16(gB + (size_t)(r * 64) * 512 + kk, Bb + (r * 512 + wv * 64) * 8);
  };

  // prologue: steps 0,1 staged; vmcnt(6) -> step0 landed (step1 may be in flight)
  STAGE(0, 0);
  STAGE(1, 1);
  asm volatile("s_waitcnt vmcnt(6)" ::: "memory");
  __builtin_amdgcn_s_barrier();

#pragma unroll
  for (int t = 0; t < 8; ++t) {
    const ushort_t* Ab = smem + (t % 3) * 24576;
    const ushort_t* Bb = Ab + 16384;
    short8 a[4][2], b[4][2];
#pragma unroll
    for (int ks = 0; ks < 2; ++ks) {
      const int co = ((((ks << 2) | lg) ^ (lr & 7)) << 3);
#pragma unroll
      for (int mi = 0; mi < 4; ++mi)
        a[mi][ks] = *(const short8*)(Ab + (wr * 64 + mi * 16 + lr) * 64 + co);
#pragma unroll
      for (int ni = 0; ni < 4; ++ni)
        b[ni][ks] = *(const short8*)(Bb + (wc * 64 + ni * 16 + lr) * 64 + co);
    }
    if (t + 2 < 8) STAGE(t + 2, (t + 2) % 3);
    if (t < 7) {
      if (t + 2 < 8) asm volatile("s_waitcnt vmcnt(6)" ::: "memory");  // step t+1 landed
      else           asm volatile("s_waitcnt vmcnt(0)" ::: "memory");  // tail drain
      asm volatile("s_waitcnt lgkmcnt(0)" ::: "memory");               // my reads done pre-barrier
      __builtin_amdgcn_s_barrier();
    }
    __builtin_amdgcn_s_setprio(1);
#pragma unroll
    for (int ks = 0; ks < 2; ++ks)
#pragma unroll
      for (int mi = 0; mi < 4; ++mi)
#pragma unroll
        for (int ni = 0; ni < 4; ++ni)
          acc[mi][ni] = __builtin_amdgcn_mfma_f32_16x16x32_bf16(a[mi][ks], b[ni][ks], acc[mi][ni], 0, 0, 0);
    __builtin_amdgcn_s_setprio(0);
  }

  // Epilogue. C layout: col=lane&15, row=(lane>>4)*4+reg.
  const int lg4 = lg << 2;
  if (n0 < 1024) {
#pragma unroll
    for (int mi = 0; mi < 4; ++mi) {
      const int rbase = m0 + wr * 64 + mi * 16 + lg4;
#pragma unroll
      for (int ni = 0; ni < 4; ++ni) {
        const int col = n0 + wc * 64 + ni * 16 + lr;
#pragma unroll
        for (int rg = 0; rg < 4; ++rg)
          qk[(size_t)(rbase + rg) * 1024 + col] = f2bf(acc[mi][ni][rg]);
      }
    }
  } else {
    const int winb = (m0 >> 7) + (wr >> 1);     // 2 windows per 256-row block
    const int t0b = (wr & 1) * 64;
#pragma unroll
    for (int mi = 0; mi < 4; ++mi) {
      const int t0 = t0b + mi * 16 + lg4;
#pragma unroll
      for (int ni = 0; ni < 4; ++ni) {
        const int c = n0 - 1024 + wc * 64 + ni * 16 + lr;  // 0..511
        const int h = c >> 6, d = c & 63;
        us4 o;
        o.x = f2bf(acc[mi][ni][0]); o.y = f2bf(acc[mi][ni][1]);
        o.z = f2bf(acc[mi][ni][2]); o.w = f2bf(acc[mi][ni][3]);
        *(us4*)(vT + (size_t)((winb * 8 + h) * 64 + d) * 128 + t0) = o;
      }
    }
  }
}

// ---------------- fused windowed causal attention (unchanged from R3) ----------------
__global__ __launch_bounds__(256) void attn_kernel(const ushort_t* __restrict__ qk,
                                                   const ushort_t* __restrict__ vT,
                                                   ushort_t* __restrict__ attn_out) {
  __shared__ __align__(16) ushort_t smem[24576];
  ushort_t* qs = smem;
  ushort_t* ks_ = smem + 8192;
  ushort_t* vs = smem + 16384;
  ushort_t* ps = smem;          // overlay q+k (written after barrier)

  const int tid = threadIdx.x;
  const int lane = tid & 63;
  const int wv = tid >> 6;
  const int win = blockIdx.x >> 3;
  const int h = blockIdx.x & 7;
  const int lr = lane & 15;
  const int lg = lane >> 4;
  const int lg4 = lg << 2;
  const int sw = lr & 7;

  // --- stage q, k (swizzled [128][64]) ---
  const size_t qbase = (size_t)win * 128 * 1024 + h * 64;
#pragma unroll
  for (int r = 0; r < 4; ++r) {
    const int g = r * 256 + tid;       // granule 0..1023
    const int t = g >> 3, ch = g & 7;
    short8 vq = *(const short8*)(qk + qbase + (size_t)t * 1024 + ch * 8);
    short8 vk = *(const short8*)(qk + qbase + 512 + (size_t)t * 1024 + ch * 8);
    const int st = t * 64 + ((ch ^ (t & 7)) << 3);
    *(short8*)(qs + st) = vq;
    *(short8*)(ks_ + st) = vk;
  }
  // --- stage v (swizzled [64][128]) ---
  const size_t vbase = (size_t)(win * 8 + h) * 64 * 128;
#pragma unroll
  for (int r = 0; r < 4; ++r) {
    const int g = r * 256 + tid;
    const int d = g >> 4, ch = g & 15;
    short8 vvv = *(const short8*)(vT + vbase + (size_t)d * 128 + ch * 8);
    *(short8*)(vs + d * 128 + ((ch ^ (d & 7)) << 3)) = vvv;
  }
  __syncthreads();

  const int rt[2] = {wv, 7 - wv};      // rt[1] > rt[0]

  // --- S = q k^T, causal col tiles only ---
  f32x4 sacc[2][8] = {};
#pragma unroll
  for (int ks2 = 0; ks2 < 2; ++ks2) {
    const int co = ((((ks2 << 2) | lg) ^ sw) << 3);
    short8 a0 = *(const short8*)(qs + (rt[0] * 16 + lr) * 64 + co);
    short8 a1 = *(const short8*)(qs + (rt[1] * 16 + lr) * 64 + co);
#pragma unroll
    for (int ni = 0; ni < 8; ++ni) {
      if (ni <= rt[1]) {
        short8 b = *(const short8*)(ks_ + (ni * 16 + lr) * 64 + co);
        if (ni <= rt[0])
          sacc[0][ni] = __builtin_amdgcn_mfma_f32_16x16x32_bf16(a0, b, sacc[0][ni], 0, 0, 0);
        sacc[1][ni] = __builtin_amdgcn_mfma_f32_16x16x32_bf16(a1, b, sacc[1][ni], 0, 0, 0);
      }
    }
  }

  __syncthreads();  // all waves done reading q/k before P overlays them

  // --- exp (unshifted; scores tiny) + causal mask; write P bf16 swizzled ---
  const float C = 0.125f * 1.44269504f;   // scale * log2(e)
#pragma unroll
  for (int mi = 0; mi < 2; ++mi) {
    const int r = rt[mi];
    const int rb = r * 16;
#pragma unroll
    for (int ni = 0; ni < 8; ++ni) {
      if (ni <= r) {
#pragma unroll
        for (int rg = 0; rg < 4; ++rg) {
          const int row = rb + lg4 + rg;
          const int col = ni * 16 + lr;
          float e = __builtin_exp2f(sacc[mi][ni][rg] * C);
          e = (col <= row) ? e : 0.0f;
          ps[row * 128 + ((((col >> 3) ^ (row & 7)) << 3) | (col & 7))] = f2bf(e);
        }
      }
    }
    if (!(r & 1)) {  // PV k32-step covers one extra 16-col tile -> zero it
      const int col = (r + 1) * 16 + lr;
#pragma unroll
      for (int rg = 0; rg < 4; ++rg) {
        const int row = rb + lg4 + rg;
        ps[row * 128 + ((((col >> 3) ^ (row & 7)) << 3) | (col & 7))] = 0;
      }
    }
  }
  // each wave reads back only the P rows it wrote -> no barrier needed

  // --- O = P V + ones-column row-sum, causal k-step limits ---
  const short one_bf = (short)0x3F80;
  short8 ones;
#pragma unroll
  for (int j = 0; j < 8; ++j) ones[j] = (lr == 0) ? one_bf : (short)0;

  f32x4 oacc[2][4] = {};
  f32x4 sm[2] = {};
#pragma unroll
  for (int ks2 = 0; ks2 < 4; ++ks2) {
    const int co = ((((ks2 << 2) | lg) ^ sw) << 3);
    if (ks2 <= (rt[1] >> 1)) {
      short8 b[4];
#pragma unroll
      for (int nd = 0; nd < 4; ++nd)
        b[nd] = *(const short8*)(vs + (nd * 16 + lr) * 128 + co);
      short8 a1 = *(const short8*)(ps + (rt[1] * 16 + lr) * 128 + co);
#pragma unroll
      for (int nd = 0; nd < 4; ++nd)
        oacc[1][nd] = __builtin_amdgcn_mfma_f32_16x16x32_bf16(a1, b[nd], oacc[1][nd], 0, 0, 0);
      sm[1] = __builtin_amdgcn_mfma_f32_16x16x32_bf16(a1, ones, sm[1], 0, 0, 0);
      if (ks2 <= (rt[0] >> 1)) {
        short8 a0 = *(const short8*)(ps + (rt[0] * 16 + lr) * 128 + co);
#pragma unroll
        for (int nd = 0; nd < 4; ++nd)
          oacc[0][nd] = __builtin_amdgcn_mfma_f32_16x16x32_bf16(a0, b[nd], oacc[0][nd], 0, 0, 0);
        sm[0] = __builtin_amdgcn_mfma_f32_16x16x32_bf16(a0, ones, sm[0], 0, 0, 0);
      }
    }
  }

  // --- epilogue: rs = 1/rowsum (broadcast from lr==0 lane of each group) ---
  const int src = lane & 48;
  const size_t obase = (size_t)win * 128 * 512 + h * 64;
#pragma unroll
  for (int mi = 0; mi < 2; ++mi) {
    const int rb = rt[mi] * 16;
    float rsv[4];
#pragma unroll
    for (int rg = 0; rg < 4; ++rg)
      rsv[rg] = 1.0f / __shfl(sm[mi][rg], src);
#pragma unroll
    for (int nd = 0; nd < 4; ++nd)
#pragma unroll
      for (int rg = 0; rg < 4; ++rg) {
        const int row = rb + lg4 + rg;
        const int col = nd * 16 + lr;
        attn_out[obase + (size_t)row * 512 + col] = f2bf(oacc[mi][nd][rg] * rsv[rg]);
      }
  }
}

// ---------------- proj GEMM: [65536,512] x [512,512]^T + bias -> fp32 out ----------------
// Same 256x128x64 3-deep pipelined structure as qkv_gemm.
// Grid: 1024 linear blocks, XCD-chunked (128/XCD), n-fastest (4 n-tiles).
__global__ __launch_bounds__(512, 2) void proj_gemm(const ushort_t* __restrict__ A,
                                                    const ushort_t* __restrict__ B,
                                                    const float* __restrict__ bias,
                                                    float* __restrict__ out) {
  __shared__ __align__(16) ushort_t smem[3 * 24576];   // 144 KB
  const int tid = threadIdx.x;
  const int lane = tid & 63;
  const int wv = tid >> 6;
  const int wr = wv >> 1, wc = wv & 1;
  const int lr = lane & 15;
  const int lg = lane >> 4;

  const int bid = blockIdx.x;
  const int wg = (bid & 7) * 128 + (bid >> 3);
  const int nb = wg & 3;
  const int mb = wg >> 2;
  const int m0 = mb << 8;
  const int n0 = nb << 7;

  const int srow = tid >> 3;
  const int ssw  = (((tid & 7) ^ (srow & 7)) << 3);
  const ushort_t* gA = A + (size_t)(m0 + srow) * 512 + ssw;
  const ushort_t* gB = B + (size_t)(n0 + srow) * 512 + ssw;

  f32x4 acc[4][4] = {};

  auto STAGE = [&](int t, int q) {
    ushort_t* Ab = smem + q * 24576;
    ushort_t* Bb = Ab + 16384;
    const int kk = t << 6;
#pragma unroll
    for (int r = 0; r < 4; ++r)
      gl_lds16(gA + (size_t)(r * 64) * 512 + kk, Ab + (r * 512 + wv * 64) * 8);
#pragma unroll
    for (int r = 0; r < 2; ++r)
      gl_lds16(gB + (size_t)(r * 64) * 512 + kk, Bb + (r * 512 + wv * 64) * 8);
  };

  STAGE(0, 0);
  STAGE(1, 1);
  asm volatile("s_waitcnt vmcnt(6)" ::: "memory");
  __builtin_amdgcn_s_barrier();

#pragma unroll
  for (int t = 0; t < 8; ++t) {
    const ushort_t* Ab = smem + (t % 3) * 24576;
    const ushort_t* Bb = Ab + 16384;
    short8 a[4][2], b[4][2];
#pragma unroll
    for (int ks = 0; ks < 2; ++ks) {
      const int co = ((((ks << 2) | lg) ^ (lr & 7)) << 3);
#pragma unroll
      for (int mi = 0; mi < 4; ++mi)
        a[mi][ks] = *(const short8*)(Ab + (wr * 64 + mi * 16 + lr) * 64 + co);
#pragma unroll
      for (int ni = 0; ni < 4; ++ni)
        b[ni][ks] = *(const short8*)(Bb + (wc * 64 + ni * 16 + lr) * 64 + co);
    }
    if (t + 2 < 8) STAGE(t + 2, (t + 2) % 3);
    if (t < 7) {
      if (t + 2 < 8) asm volatile("s_waitcnt vmcnt(6)" ::: "memory");
      else           asm volatile("s_waitcnt vmcnt(0)" ::: "memory");
      asm volatile("s_waitcnt lgkmcnt(0)" ::: "memory");
      __builtin_amdgcn_s_barrier();
    }
    __builtin_amdgcn_s_setprio(1);
#pragma unroll
    for (int ks = 0; ks < 2; ++ks)
#pragma unroll
      for (int mi = 0; mi < 4; ++mi)
#pragma unroll
        for (int ni = 0; ni < 4; ++ni)
          acc[mi][ni] = __builtin_amdgcn_mfma_f32_16x16x32_bf16(a[mi][ks], b[ni][ks], acc[mi][ni], 0, 0, 0);
    __builtin_amdgcn_s_setprio(0);
  }

  const int lg4 = lg << 2;
#pragma unroll
  for (int mi = 0; mi < 4; ++mi) {
    const int rbase = m0 + wr * 64 + mi * 16 + lg4;
#pragma unroll
    for (int ni = 0; ni < 4; ++ni) {
      const int col = n0 + wc * 64 + ni * 16 + lr;
      const float bv = bias[col];
#pragma unroll
      for (int rg = 0; rg < 4; ++rg)
        out[(size_t)(rbase + rg) * 512 + col] = acc[mi][ni][rg] + bv;
    }
  }
}

extern "C" void kernel_launch(void* const* d_in, const int* in_sizes, int n_in,
                              void* d_out, int out_size, void* d_ws, size_t ws_size,
                              hipStream_t stream) {
  const float* x      = (const float*)d_in[0];
  const float* w_qkv  = (const float*)d_in[1];
  const float* w_proj = (const float*)d_in[2];
  const float* b_proj = (const float*)d_in[3];
  float* out = (float*)d_out;

  char* ws = (char*)d_ws;
  ushort_t* x_bf     = (ushort_t*)(ws);
  ushort_t* qk_ws    = (ushort_t*)(ws + 67108864);
  ushort_t* vT_ws    = (ushort_t*)(ws + 67108864 + 134217728);
  ushort_t* attn_ws  = (ushort_t*)(ws + 67108864 + 134217728 + 67108864);
  ushort_t* wqkv_bf  = (ushort_t*)(ws + 335544320);
  ushort_t* wproj_bf = (ushort_t*)(ws + 337117184);

  cast_f32_bf16<<<32768, 256, 0, stream>>>(x, x_bf, 8388608);
  cast_f32_bf16<<<768, 256, 0, stream>>>(w_qkv, wqkv_bf, 196608);
  cast_f32_bf16<<<256, 256, 0, stream>>>(w_proj, wproj_bf, 65536);

  qkv_gemm<<<3072, 512, 0, stream>>>(x_bf, wqkv_bf, qk_ws, vT_ws);
  attn_kernel<<<4096, 256, 0, stream>>>(qk_ws, vT_ws, attn_ws);
  proj_gemm<<<1024, 512, 0, stream>>>(attn_ws, wproj_bf, b_proj, out);
}